// Round 9
// baseline (13.816 us; speedup 1.0000x reference)
//
#include <hip/hip_runtime.h>

#define NS 32
#define NH 32
#define C2L 2.8853900817779268f  // 2*log2(e): e^(2x) = 2^(C2L*x)

// 256 blocks (1/CU) x 256 threads, 2 points per thread (n, n+N/2) with fully
// interleaved computation: 2 independent dependency streams per lane fill the
// trans/LDS pipes at 1 wave/SIMD, and staging instances halve vs R7 (the
// R6->R8 A/B measured ~3.5us per 512 staging instances).
__global__ __launch_bounds__(256) void springnn_kernel(
    const float* __restrict__ t_in,
    const float* __restrict__ W1,   // [S][1][H]
    const float* __restrict__ b1,   // [S][H]
    const float* __restrict__ W2,   // [S][H][1]
    const float* __restrict__ b2,   // [S][1]
    float* __restrict__ out,
    int N)
{
    __shared__ float2 w1b1[NH][NS + 1];     // [h][s] = (W1*C2L, b1*C2L)
    __shared__ float2 w2p[NH / 2][NS + 1];  // [h2][s] = (-2*W2[2h2], -2*W2[2h2+1])
    __shared__ float  b2eff[NS];            // b2[s] + sum_h W2[s][h] (tanh folding)

    const int tid = threadIdx.x;

    // ---- stage: h-fast decode -> coalesced global; padded rows -> low-conflict writes ----
    #pragma unroll
    for (int it = 0; it < 4; ++it) {
        const int idx = it * 256 + tid;
        const int s = idx >> 5;
        const int h = idx & 31;
        w1b1[h][s] = make_float2(W1[s * NH + h] * C2L, b1[s * NH + h] * C2L);
        ((float*)&w2p[h >> 1][s])[h & 1] = -2.0f * W2[s * NH + h];
    }
    if (tid < NS) {
        float acc = b2[tid];
        const float4* w2v = (const float4*)(W2 + tid * NH);
        #pragma unroll
        for (int q = 0; q < NH / 4; ++q) {
            float4 v = w2v[q];
            acc += (v.x + v.y) + (v.z + v.w);
        }
        b2eff[tid] = acc;
    }
    __syncthreads();

    const int half = (N + 1) >> 1;
    const int nA = blockIdx.x * 256 + tid;
    const int nB = nA + half;
    if (nA >= half) return;
    const bool vB = (nB < N);
    const float tA = t_in[nA];
    const float tB = vB ? t_in[nB] : 0.0f;

    const int s0A = (int)ceilf(tA - 2.0f);
    const int s0B = (int)ceilf(tB - 2.0f);

    float outA = 0.0f, outB = 0.0f;
    #pragma unroll
    for (int j = 0; j < 4; ++j) {
        const int sA = s0A + j;
        const int sB = s0B + j;
        const bool okA = ((unsigned)sA < (unsigned)NS);
        const bool okB = ((unsigned)sB < (unsigned)NS);
        const int scA = okA ? sA : 0;
        const int scB = okB ? sB : 0;
        // window = (1+cos(pi*d/2))/2 ; v_cos takes revolutions -> arg d/4
        const float cA = __builtin_amdgcn_cosf((tA - (float)sA) * 0.25f);
        const float cB = __builtin_amdgcn_cosf((tB - (float)sB) * 0.25f);
        const float wA = okA ? fmaf(0.5f, cA, 0.5f) : 0.0f;
        const float wB = okB ? fmaf(0.5f, cB, 0.5f) : 0.0f;

        float oA0 = b2eff[scA], oA1 = 0.0f;
        float oB0 = b2eff[scB], oB1 = 0.0f;
        #pragma unroll
        for (int h2 = 0; h2 < NH / 2; ++h2) {
            const float2 waA = w1b1[2 * h2][scA];
            const float2 wbA = w1b1[2 * h2 + 1][scA];
            const float2 wqA = w2p[h2][scA];
            const float2 waB = w1b1[2 * h2][scB];
            const float2 wbB = w1b1[2 * h2 + 1][scB];
            const float2 wqB = w2p[h2][scB];
            const float eaA = __builtin_amdgcn_exp2f(fmaf(tA, waA.x, waA.y));
            const float ebA = __builtin_amdgcn_exp2f(fmaf(tA, wbA.x, wbA.y));
            const float eaB = __builtin_amdgcn_exp2f(fmaf(tB, waB.x, waB.y));
            const float ebB = __builtin_amdgcn_exp2f(fmaf(tB, wbB.x, wbB.y));
            oA0 = fmaf(wqA.x, __builtin_amdgcn_rcpf(eaA + 1.0f), oA0);
            oA1 = fmaf(wqA.y, __builtin_amdgcn_rcpf(ebA + 1.0f), oA1);
            oB0 = fmaf(wqB.x, __builtin_amdgcn_rcpf(eaB + 1.0f), oB0);
            oB1 = fmaf(wqB.y, __builtin_amdgcn_rcpf(ebB + 1.0f), oB1);
        }
        outA = fmaf(wA, oA0 + oA1, outA);
        outB = fmaf(wB, oB0 + oB1, outB);
    }
    out[nA] = outA;
    if (vB) out[nB] = outB;
}

extern "C" void kernel_launch(void* const* d_in, const int* in_sizes, int n_in,
                              void* d_out, int out_size, void* d_ws, size_t ws_size,
                              hipStream_t stream) {
    const float* t  = (const float*)d_in[0];
    const float* W1 = (const float*)d_in[1];
    const float* b1 = (const float*)d_in[2];
    const float* W2 = (const float*)d_in[3];
    const float* b2 = (const float*)d_in[4];
    float* outp = (float*)d_out;
    const int N = in_sizes[0];

    const int block = 256;
    const int half = (N + 1) >> 1;
    const int grid = (half + block - 1) / block;
    springnn_kernel<<<grid, block, 0, stream>>>(t, W1, b1, W2, b2, outp, N);
}